// Round 7
// baseline (2018.901 us; speedup 1.0000x reference)
//
// NeRTModel_60997125538302 — round 7: fix i8 dequant scale (round 6 was 127x too hot).
// Gate = sum(W_q*h_q) * mx/127^2;  round 6 stored scl = mx/127 (missing h-quant 1/127)
// -> all gates saturated -> garbage. One-line fix in k0b: scl = mx/16129.
// k4 design unchanged: i8 MFMA 16x16x64, 3 reg pairs (48 VGPR) + 28 pairs in 112KB LDS
// pool, fits the 128-VGPR budget honestly; h8 stride-272 kills bank conflicts.

#include <hip/hip_runtime.h>
#include <hip/hip_bf16.h>
#include <cstdint>
#include <cstddef>

typedef unsigned short u16;
typedef __attribute__((ext_vector_type(8))) short short8v;
typedef __attribute__((ext_vector_type(4))) short short4v;
typedef __attribute__((ext_vector_type(4))) float f32x4;
typedef __attribute__((ext_vector_type(4))) int i32x4;

#define MFMA16 __builtin_amdgcn_mfma_f32_16x16x32_bf16
#define MFMAI8 __builtin_amdgcn_mfma_i32_16x16x64_i8

__device__ __forceinline__ float bf2f(u16 u){
  union { unsigned int i; float f; } v; v.i = ((unsigned int)u) << 16; return v.f;
}
__device__ __forceinline__ u16 f2bf(float f){
  union { float f; unsigned int u; } v; v.f = f;
  unsigned int r = v.u + 0x7FFFu + ((v.u >> 16) & 1u);
  return (u16)(r >> 16);
}
__device__ __forceinline__ short8v szero(){
  short8v z;
  #pragma unroll
  for (int i = 0; i < 8; i++) z[i] = 0;
  return z;
}
__device__ __forceinline__ float sigm(float x){ return 1.0f/(1.0f + __expf(-x)); }
__device__ __forceinline__ float tanh_u(float x){
  float e = __expf(2.f*x);              // overflow -> inf -> tanh -> 1 (no NaN)
  return 1.f - 2.f/(e + 1.f);
}

// ---------------- K0: convert non-recurrent weights f32 -> bf16; fuse LSTM biases ----------------
__global__ void k0_cvt(const float* __restrict__ wq, const float* __restrict__ wk,
                       const float* __restrict__ wihf, const float* __restrict__ wihb,
                       const float* __restrict__ bihf, const float* __restrict__ bhhf,
                       const float* __restrict__ bihb, const float* __restrict__ bhhb,
                       u16* __restrict__ wqb, u16* __restrict__ wkb,
                       u16* __restrict__ wihfb, u16* __restrict__ wihbb,
                       float* __restrict__ bgf, float* __restrict__ bgb){
  int i = blockIdx.x*256 + threadIdx.x;
  if (i < 160000){ wqb[i] = f2bf(wq[i]); wkb[i] = f2bf(wk[i]); }
  if (i < 320000){ wihfb[i] = f2bf(wihf[i]); wihbb[i] = f2bf(wihb[i]); }
  if (i < 800){ bgf[i] = bihf[i] + bhhf[i]; bgb[i] = bihb[i] + bhhb[i]; }
}

// ---------------- K0b: row-quantize W_hh -> i8 [4 gate][208 row][256 k] + scales ----------------
__global__ void k0b_quant(const float* __restrict__ whhf, const float* __restrict__ whhb,
                          signed char* __restrict__ w8f, signed char* __restrict__ w8b,
                          float* __restrict__ sclf, float* __restrict__ sclb){
  const int tid = threadIdx.x, lane = tid & 63, wv = tid >> 6;
  const int widx = blockIdx.x*4 + wv;              // 0..1663
  if (widx < 1600){
    int dir = widx / 800, g = widx - dir*800;
    const float* src = (dir ? whhb : whhf) + (size_t)g*200;
    float mx = 0.f;
    for (int j = lane; j < 200; j += 64) mx = fmaxf(mx, fabsf(src[j]));
    #pragma unroll
    for (int m = 32; m > 0; m >>= 1) mx = fmaxf(mx, __shfl_xor(mx, m, 64));
    float inv = (mx > 0.f) ? 127.f/mx : 0.f;
    int gt = g / 200, hl = g - gt*200;
    signed char* dst = (dir ? w8b : w8f) + (size_t)(gt*208 + hl)*256;
    int e0 = lane*4;
    unsigned int pack = 0u;
    if (e0 < 200){
      #pragma unroll
      for (int r = 0; r < 4; r++){
        int qv = __float2int_rn(src[e0+r]*inv);
        pack |= ((unsigned int)(qv & 255)) << (8*r);
      }
    }
    ((unsigned int*)dst)[lane] = pack;               // lanes 50..63 zero the k-pad
    // dequant scale for acc = sum(W_q * h_q): W ~ W_q*mx/127, h ~ h_q/127
    if (lane == 0) (dir ? sclb : sclf)[g] = mx / 16129.f;   // mx / 127^2
  } else {
    int pr = widx - 1600;                            // 64 pad rows (2 dir x 4 gt x 8)
    int dir = pr >> 5, rem = pr & 31, gt = rem >> 3, hl = 200 + (rem & 7);
    signed char* dst = (dir ? w8b : w8f) + (size_t)(gt*208 + hl)*256;
    ((unsigned int*)dst)[lane] = 0u;
  }
}

// ---------------- K1: per-news word-attention pooling (2 news per block) ----------------
__launch_bounds__(256)
__global__ void k1_pool(const float* __restrict__ x2,
                        const u16* __restrict__ wqb, const float* __restrict__ bq,
                        const u16* __restrict__ wkb, const float* __restrict__ bk,
                        float* __restrict__ pooled){
  __shared__ u16 tok[2][6400];
  __shared__ u16 qs [2][6400];
  __shared__ u16 kss[2][6400];
  __shared__ u16 probs[2][5120];
  __shared__ float msum[2][256];
  __shared__ float tval[2][16];
  __shared__ float attw[2][16];
  const int tid = threadIdx.x;
  const size_t n0 = (size_t)blockIdx.x * 2;
  const float* src = x2 + n0*6400;
  for (int i = tid; i < 3200; i += 256){
    f32x4 v = *(const f32x4*)&src[(size_t)i*4];
    short4v s; s[0]=f2bf(v[0]); s[1]=f2bf(v[1]); s[2]=f2bf(v[2]); s[3]=f2bf(v[3]);
    int j = i / 1600, r = i - j*1600;
    ((short4v*)tok[j])[r] = s;
  }
  __syncthreads();

  const int lane = tid & 63, wv = tid >> 6;
  const int q = lane & 15, kg = lane >> 4;
  {
    const int proj = wv >> 1;                 // 0: q, 1: k
    const int ntbase = (wv & 1) ? 13 : 0;
    const int ntcnt  = (wv & 1) ? 12 : 13;    // 25 col-tiles total
    const u16* W    = proj ? wkb : wqb;
    const float* bias = proj ? bk : bq;
    short8v A[2][13];
    #pragma unroll
    for (int j = 0; j < 2; j++)
      #pragma unroll
      for (int ksi = 0; ksi < 13; ksi++){
        int e0 = ksi*32 + kg*8;
        A[j][ksi] = (e0 < 400) ? *(const short8v*)&tok[j][q*400 + e0] : szero();
      }
    u16* d0 = proj ? kss[0] : qs[0];
    u16* d1 = proj ? kss[1] : qs[1];
    for (int ti = 0; ti < ntcnt; ti++){
      int col = (ntbase + ti)*16 + q;
      float bv = bias[col];
      f32x4 acc0, acc1;
      acc0[0]=bv; acc0[1]=bv; acc0[2]=bv; acc0[3]=bv; acc1 = acc0;
      const u16* wrow = W + (size_t)col*400;
      #pragma unroll
      for (int ksi = 0; ksi < 13; ksi++){
        int e0 = ksi*32 + kg*8;
        short8v bf = (e0 < 400) ? *(const short8v*)&wrow[e0] : szero();
        acc0 = MFMA16(A[0][ksi], bf, acc0, 0, 0, 0);
        acc1 = MFMA16(A[1][ksi], bf, acc1, 0, 0, 0);
      }
      #pragma unroll
      for (int r = 0; r < 4; r++){          // D: row=(l>>4)*4+r, col=l&15
        d0[(kg*4+r)*400 + col] = f2bf(acc0[r]);
        d1[(kg*4+r)*400 + col] = f2bf(acc1[r]);
      }
    }
  }
  __syncthreads();
  // scores per (news, head, sq): dot20 over head dims, softmax over sk
  for (int r0 = tid; r0 < 640; r0 += 256){
    int j = r0 / 320, rem = r0 - j*320;
    int hh = rem >> 4, sq = rem & 15;
    const u16* qrow = &qs[j][sq*400 + hh*20];
    float qv[20];
    #pragma unroll
    for (int d5 = 0; d5 < 5; d5++){
      short4v v = *(const short4v*)&qrow[d5*4];
      qv[d5*4+0]=bf2f((u16)v[0]); qv[d5*4+1]=bf2f((u16)v[1]);
      qv[d5*4+2]=bf2f((u16)v[2]); qv[d5*4+3]=bf2f((u16)v[3]);
    }
    float sc[16]; float mx = -1e30f;
    #pragma unroll
    for (int sk = 0; sk < 16; sk++){
      const u16* krow = &kss[j][sk*400 + hh*20];
      float s = 0.f;
      #pragma unroll
      for (int d5 = 0; d5 < 5; d5++){
        short4v v = *(const short4v*)&krow[d5*4];
        s += qv[d5*4+0]*bf2f((u16)v[0]) + qv[d5*4+1]*bf2f((u16)v[1])
           + qv[d5*4+2]*bf2f((u16)v[2]) + qv[d5*4+3]*bf2f((u16)v[3]);
      }
      s *= 0.22360679775f;                   // 1/sqrt(20)
      sc[sk] = s; mx = fmaxf(mx, s);
    }
    float sum = 0.f;
    #pragma unroll
    for (int sk = 0; sk < 16; sk++){ sc[sk] = __expf(sc[sk]-mx); sum += sc[sk]; }
    float inv = 1.f/sum;
    #pragma unroll
    for (int sk = 0; sk < 16; sk++) probs[j][(hh*16+sq)*16 + sk] = f2bf(sc[sk]*inv);
  }
  __syncthreads();
  #pragma unroll
  for (int it = 0; it < 2; it++){            // mean over heads
    int idx = tid + it*256;
    int j = idx >> 8, sq = (idx >> 4) & 15, sk = idx & 15;
    float s = 0.f;
    #pragma unroll
    for (int hh = 0; hh < 20; hh++) s += bf2f(probs[j][(hh*16+sq)*16 + sk]);
    msum[j][sq*16+sk] = s * 0.05f;
  }
  __syncthreads();
  if (tid < 32){                             // mean over sk
    int j = tid >> 4, sq = tid & 15;
    float s = 0.f;
    #pragma unroll
    for (int sk = 0; sk < 16; sk++) s += msum[j][sq*16+sk];
    tval[j][sq] = s * 0.0625f;
  }
  __syncthreads();
  if (tid < 2){                              // softmax over sq (16 values)
    float mx = -1e30f;
    for (int i = 0; i < 16; i++) mx = fmaxf(mx, tval[tid][i]);
    float sum = 0.f; float ev[16];
    for (int i = 0; i < 16; i++){ ev[i] = __expf(tval[tid][i]-mx); sum += ev[i]; }
    float inv = 1.f/sum;
    for (int i = 0; i < 16; i++) attw[tid][i] = ev[i]*inv;
  }
  __syncthreads();
  for (int e = tid; e < 800; e += 256){
    int j = e / 400, c = e - j*400;
    float acc = 0.f;
    #pragma unroll
    for (int s = 0; s < 16; s++) acc += attw[j][s]*bf2f(tok[j][s*400 + c]);
    pooled[(n0+j)*400 + c] = acc;
  }
}

// ---------------- K2: x2p = pooled @ w_mlp_mha^T + b (f32 VALU) ----------------
__global__ void k2_x2p(const float* __restrict__ pooled, const float* __restrict__ wmha,
                       const float* __restrict__ bmha, float* __restrict__ x2p){
  __shared__ float rows[3200];
  const int tid = threadIdx.x;
  const size_t n0 = (size_t)blockIdx.x*8;
  for (int i = tid; i < 3200; i += 256) rows[i] = pooled[n0*400 + i];
  __syncthreads();
  for (int j = tid; j < 400; j += 256){
    float bv = bmha[j];
    float acc[8];
    #pragma unroll
    for (int r = 0; r < 8; r++) acc[r] = bv;
    const float* wr = wmha + (size_t)j*400;
    for (int e = 0; e < 400; e += 4){
      const f32x4 w4 = *(const f32x4*)&wr[e];
      #pragma unroll
      for (int r = 0; r < 8; r++){
        const f32x4 x4 = *(const f32x4*)&rows[r*400 + e];
        acc[r] += x4[0]*w4[0] + x4[1]*w4[1] + x4[2]*w4[2] + x4[3]*w4[3];
      }
    }
    #pragma unroll
    for (int r = 0; r < 8; r++) x2p[(n0+r)*400 + j] = acc[r];
  }
}

// ---------------- K3: xW = x @ W_ih^T + (b_ih+b_hh), layout [t][grp][b16][hu4][gt][4] bf16 ----------------
__launch_bounds__(512)
__global__ void k3_xw(const float* __restrict__ x1, const int* __restrict__ seq,
                      const u16* __restrict__ wihfb, const u16* __restrict__ wihbb,
                      const float* __restrict__ bgf, const float* __restrict__ bgb,
                      u16* __restrict__ xWf, u16* __restrict__ xWb){
  __shared__ u16 xf[12800];
  __shared__ u16 xb[12800];
  const int tid = threadIdx.x;
  const int t = blockIdx.x;
  for (int i = tid; i < 3200; i += 512){
    int b = i / 100, e4 = i - b*100;
    f32x4 vf = *(const f32x4*)&x1[((size_t)b*256 + t)*400 + e4*4];
    int rb = seq[b] - 1 - t; if (rb < 0) rb = 0;     // clip(L-1-t, 0, T-1)
    f32x4 vb = *(const f32x4*)&x1[((size_t)b*256 + rb)*400 + e4*4];
    short4v sf, sb;
    #pragma unroll
    for (int r = 0; r < 4; r++){ sf[r] = f2bf(vf[r]); sb[r] = f2bf(vb[r]); }
    ((short4v*)xf)[i] = sf;
    ((short4v*)xb)[i] = sb;
  }
  __syncthreads();
  const int lane = tid & 63, wv = tid >> 6;
  const int dir = wv >> 2, wl = wv & 3;
  const u16* xs = dir ? xb : xf;
  const u16* W  = dir ? wihbb : wihfb;
  const float* bg = dir ? bgb : bgf;
  u16* xW = dir ? xWb : xWf;
  const int q = lane & 15, kg = lane >> 4;
  short8v A[2][13];
  #pragma unroll
  for (int mt = 0; mt < 2; mt++)
    #pragma unroll
    for (int ksi = 0; ksi < 13; ksi++){
      int e0 = ksi*32 + kg*8;
      A[mt][ksi] = (e0 < 400) ? *(const short8v*)&xs[(mt*16 + q)*400 + e0] : szero();
    }
  for (int nt = wl; nt < 50; nt += 4){
    int g = nt*16 + q;                       // gate row 0..799 (i,f,g,o blocks of 200)
    float bv = bg[g];
    f32x4 acc0, acc1;
    acc0[0]=bv; acc0[1]=bv; acc0[2]=bv; acc0[3]=bv; acc1 = acc0;
    const u16* wrow = W + (size_t)g*400;
    #pragma unroll
    for (int ksi = 0; ksi < 13; ksi++){
      int e0 = ksi*32 + kg*8;
      short8v bf = (e0 < 400) ? *(const short8v*)&wrow[e0] : szero();
      acc0 = MFMA16(A[0][ksi], bf, acc0, 0,0,0);
      acc1 = MFMA16(A[1][ksi], bf, acc1, 0,0,0);
    }
    int gt = g / 200, hu = g - gt*200;
    int hu4 = hu >> 2, rr = hu & 3;
    #pragma unroll
    for (int r = 0; r < 4; r++){
      int bl = kg*4 + r;                     // D rows = batch rows (mt*16 + bl)
      xW[((((size_t)t*2 + 0)*16 + bl)*50 + hu4)*16 + gt*4 + rr] = f2bf(acc0[r]);
      xW[((((size_t)t*2 + 1)*16 + bl)*50 + hu4)*16 + gt*4 + rr] = f2bf(acc1[r]);
    }
  }
}

// ---------------- K4: sequential BiLSTM, i8 MFMA. grid 4 = (dir, grp16), 512 thr. ----------------
__device__ __forceinline__ void store_gate(int p, const i32x4& acc, int q, int kg,
                                           u16* gates, const float* scl_s){
  int gt = p/13, nt = p - gt*13;
  int hu0 = nt*16 + kg*4;
  if (hu0 < 200){
    const f32x4 s4 = *(const f32x4*)&scl_s[gt*200 + hu0];
    short4v g4;
    #pragma unroll
    for (int r = 0; r < 4; r++) g4[r] = (short)f2bf((float)acc[r]*s4[r]);
    *(short4v*)&gates[(gt*16 + q)*200 + hu0] = g4;     // q = batch (D col)
  }
}

__launch_bounds__(512)
__global__ void k4_lstm(const u16* __restrict__ xWf, const u16* __restrict__ xWb,
                        const signed char* __restrict__ w8f, const signed char* __restrict__ w8b,
                        const float* __restrict__ sclf, const float* __restrict__ sclb,
                        const int* __restrict__ seq, float* __restrict__ h_ws){
  __shared__ __align__(16) signed char h8[16*272];     // h_{t-1} i8, stride 272 (bank-spread)
  __shared__ __align__(16) u16 gates[12800];           // [gt][b16][hu200] bf16
  __shared__ __align__(16) i32x4 pool[28*4*64];        // pairs 24..51 fragment pool (112KB)
  __shared__ float scl_s[800];
  __shared__ int Ls[16];
  const int tid = threadIdx.x;
  const int dir = blockIdx.x >> 1, grp = blockIdx.x & 1;
  const u16* xWd = dir ? xWb : xWf;
  const signed char* w8 = dir ? w8b : w8f;
  const float* scl = dir ? sclb : sclf;
  if (tid < 16) Ls[tid] = seq[grp*16 + tid];
  for (int i = tid; i < 1088; i += 512) ((int*)h8)[i] = 0;
  for (int i = tid; i < 800; i += 512) scl_s[i] = scl[i];
  const int lane = tid & 63, wv = tid >> 6;
  const int q = lane & 15, kg = lane >> 4;
  // pool fill: slot s holds pair p = 24+s (A-fragment order, conflict-free b128 reads)
  for (int idx = tid; idx < 28*4*64; idx += 512){
    int s = idx >> 8, rem = idx & 255;
    int ksi = rem >> 6, l = rem & 63;
    int qq = l & 15, kk = l >> 4;
    int p = 24 + s, gt = p/13, nt = p - gt*13;
    pool[idx] = *(const i32x4*)&w8[(size_t)(gt*208 + nt*16 + qq)*256 + ksi*64 + kk*16];
  }
  // register pairs p = wv + 8j, j<3 (48 VGPR)
  i32x4 Wr[3][4];
  #pragma unroll
  for (int j = 0; j < 3; j++){
    int p = wv + 8*j, gt = p/13, nt = p - gt*13;
    #pragma unroll
    for (int ksi = 0; ksi < 4; ksi++)
      Wr[j][ksi] = *(const i32x4*)&w8[(size_t)(gt*208 + nt*16 + q)*256 + ksi*64 + kg*16];
  }
  float cst[8];
  #pragma unroll
  for (int i = 0; i < 8; i++) cst[i] = 0.f;
  const int bl0 = tid / 50,  hu40 = tid - bl0*50;          // quad 0 (always valid)
  const int qd1 = tid + 512;
  const int bl1 = qd1 / 50,  hu41 = qd1 - bl1*50;          // quad 1 (tid<288)
  __syncthreads();
  #pragma unroll 1
  for (int t = 0; t < 256; t++){
    const u16* xwt = xWd + ((size_t)t*2 + grp)*12800;
    short8v xw0a = *(const short8v*)&xwt[tid*16];
    short8v xw0b = *(const short8v*)&xwt[tid*16 + 8];
    // h_{t-1} B-fragments (shared by all of this wave's pairs)
    i32x4 bh[4];
    #pragma unroll
    for (int ksi = 0; ksi < 4; ksi++)
      bh[ksi] = *(const i32x4*)&h8[q*272 + ksi*64 + kg*16];
    // 3 register pairs
    #pragma unroll
    for (int j = 0; j < 3; j++){
      i32x4 acc = {0,0,0,0};
      #pragma unroll
      for (int ksi = 0; ksi < 4; ksi++)
        acc = MFMAI8(Wr[j][ksi], bh[ksi], acc, 0,0,0);
      store_gate(wv + 8*j, acc, q, kg, gates, scl_s);
    }
    // 3 pool pairs (all waves)
    #pragma unroll
    for (int jp = 0; jp < 3; jp++){
      int s = wv + 8*jp;
      i32x4 acc = {0,0,0,0};
      #pragma unroll
      for (int ksi = 0; ksi < 4; ksi++)
        acc = MFMAI8(pool[(s*4 + ksi)*64 + lane], bh[ksi], acc, 0,0,0);
      store_gate(24 + s, acc, q, kg, gates, scl_s);
    }
    // 4 leftover pool pairs on waves 0..3
    if (wv < 4){
      int s = 24 + wv;
      i32x4 acc = {0,0,0,0};
      #pragma unroll
      for (int ksi = 0; ksi < 4; ksi++)
        acc = MFMAI8(pool[(s*4 + ksi)*64 + lane], bh[ksi], acc, 0,0,0);
      store_gate(24 + s, acc, q, kg, gates, scl_s);
    }
    __syncthreads();                                   // gates + xw0 ready
    // quad-1 xW loads issued now; latency hides under quad-0 activation
    short8v xw1a = szero(), xw1b = szero();
    if (tid < 288){
      xw1a = *(const short8v*)&xwt[qd1*16];
      xw1b = *(const short8v*)&xwt[qd1*16 + 8];
    }
    {
      int base = bl0*200 + hu40*4;
      short4v gi4 = *(const short4v*)&gates[base];
      short4v gf4 = *(const short4v*)&gates[3200 + base];
      short4v gg4 = *(const short4v*)&gates[6400 + base];
      short4v go4 = *(const short4v*)&gates[9600 + base];
      unsigned int hp8 = 0u; f32x4 hw;
      #pragma unroll
      for (int r = 0; r < 4; r++){
        float gi = bf2f((u16)gi4[r]) + bf2f((u16)xw0a[r]);
        float gf = bf2f((u16)gf4[r]) + bf2f((u16)xw0a[4+r]);
        float gg = bf2f((u16)gg4[r]) + bf2f((u16)xw0b[r]);
        float go = bf2f((u16)go4[r]) + bf2f((u16)xw0b[4+r]);
        float c = sigm(gf)*cst[r] + sigm(gi)*tanh_u(gg);
        cst[r] = c;
        float hv = sigm(go)*tanh_u(c);
        hp8 |= ((unsigned int)(__float2int_rn(hv*127.f) & 255)) << (8*r);
        hw[r] = hv;
      }
      *(unsigned int*)&h8[bl0*272 + hu40*4] = hp8;
      int gb = grp*16 + bl0;
      if (dir == 0){
        *(f32x4*)&h_ws[((size_t)gb*256 + t)*400 + hu40*4] = hw;
      } else {
        int tp = Ls[bl0] - 1 - t;
        if (tp >= 0) *(f32x4*)&h_ws[((size_t)gb*256 + tp)*400 + 200 + hu40*4] = hw;
      }
    }
    if (tid < 288){
      int base = bl1*200 + hu41*4;
      short4v gi4 = *(const short4v*)&gates[base];
      short4v gf4 = *(const short4v*)&gates[3200 + base];
      short4v gg4 = *(const short4v*)&gates[6400 + base];
      short4v go4 = *(const short4v*)&gates[9600 + base];
      unsigned int hp8 = 0u; f32x4 hw;
      #pragma unroll
      for (int r = 0; r < 4; r++){
        float gi = bf2f((u16)gi4[r]) + bf2f((u16)xw1a[r]);
        float gf = bf2f((u16)gf4[r]) + bf2f((u16)xw1a[4+r]);
        float gg = bf2f((u16)gg4[r]) + bf2f((u16)xw1b[r]);
        float go = bf2f((u16)go4[r]) + bf2f((u16)xw1b[4+r]);
        float c = sigm(gf)*cst[4+r] + sigm(gi)*tanh_u(gg);
        cst[4+r] = c;
        float hv = sigm(go)*tanh_u(c);
        hp8 |= ((unsigned int)(__float2int_rn(hv*127.f) & 255)) << (8*r);
        hw[r] = hv;
      }
      *(unsigned int*)&h8[bl1*272 + hu41*4] = hp8;
      int gb = grp*16 + bl1;
      if (dir == 0){
        *(f32x4*)&h_ws[((size_t)gb*256 + t)*400 + hu41*4] = hw;
      } else {
        int tp = Ls[bl1] - 1 - t;
        if (tp >= 0) *(f32x4*)&h_ws[((size_t)gb*256 + tp)*400 + 200 + hu41*4] = hw;
      }
    }
    __syncthreads();                                   // h8 ready for t+1
  }
}

// ---------------- K4b: fill bwd rows t>=L with h_bwd_r[0] (== stored row L-1) ----------------
__global__ void k4b_fill(const int* __restrict__ seq, float* __restrict__ h_ws){
  const int b = blockIdx.x;
  const int L = seq[b];
  const int cnt = (256 - L)*200;
  const float* src = h_ws + ((size_t)b*256 + (L-1))*400 + 200;
  for (int i = threadIdx.x; i < cnt; i += 256){
    int tt = L + i/200, cc = i - (i/200)*200;
    h_ws[((size_t)b*256 + tt)*400 + 200 + cc] = src[cc];
  }
}

// ---------------- K5: causal growing-window attention (query term cancels) ----------------
__launch_bounds__(512)
__global__ void k5_attn(const float* __restrict__ h_ws, const float* __restrict__ wattn,
                        float* __restrict__ x1_att){
  __shared__ float a_lds[256];
  const int tid = threadIdx.x;
  const int b = blockIdx.x;
  const int lane = tid & 63, wv = tid >> 6;
  for (int row = wv*32; row < wv*32 + 32; row++){
    float s = 0.f;
    for (int j = lane; j < 400; j += 64)
      s += h_ws[((size_t)b*256 + row)*400 + j] * wattn[j];
    #pragma unroll
    for (int m = 32; m > 0; m >>= 1) s += __shfl_xor(s, m, 64);
    if (lane == 0) a_lds[row] = s;
  }
  __syncthreads();
  const int col = tid;
  const bool act = col < 400;
  float m = -1e30f, den = 0.f, num = 0.f;
  const float* hb = h_ws + (size_t)b*256*400 + col;
  float* ob = x1_att + (size_t)b*256*400 + col;
  float hvA = act ? hb[0] : 0.f;
  float hvB = act ? hb[400] : 0.f;
  for (int t = 0; t < 256; t++){
    float hv = hvA; hvA = hvB;
    hvB = (act && t + 2 < 256) ? hb[(size_t)(t+2)*400] : 0.f;
    float at = a_lds[t];
    float mn = fmaxf(m, at);
    float rr  = __expf(m - mn);
    float wgt = __expf(at - mn);
    den = den*rr + wgt;
    num = num*rr + wgt*hv;
    m = mn;
    if (act) ob[(size_t)t*400] = num/den;
  }
}

// ---------------- K6: out = [x1_att ; x2p] @ w_mlp^T + b, masked, f32 ----------------
__global__ void k6_out(const float* __restrict__ x1_att, const float* __restrict__ x2p,
                       const float* __restrict__ wmlp, const float* __restrict__ bmlp,
                       const int* __restrict__ seq, float* __restrict__ out){
  __shared__ float rows[8*800];
  const int tid = threadIdx.x;
  const size_t n0 = (size_t)blockIdx.x*8;
  const int b = (int)(n0 >> 8), t0 = (int)(n0 & 255);
  const int L = seq[b];
  for (int i = tid; i < 3200; i += 256){
    int r = i / 400, e = i - r*400;
    rows[r*800 + e]       = x1_att[(n0 + r)*400 + e];
    rows[r*800 + 400 + e] = x2p  [(n0 + r)*400 + e];
  }
  __syncthreads();
  for (int e = tid; e < 400; e += 256){
    float bv = bmlp[e];
    float acc[8];
    #pragma unroll
    for (int r = 0; r < 8; r++) acc[r] = bv;
    const float* wr = wmlp + (size_t)e*800;
    for (int j = 0; j < 800; j += 4){
      const f32x4 w4 = *(const f32x4*)&wr[j];
      #pragma unroll
      for (int r = 0; r < 8; r++){
        const f32x4 x4 = *(const f32x4*)&rows[r*800 + j];
        acc[r] += x4[0]*w4[0] + x4[1]*w4[1] + x4[2]*w4[2] + x4[3]*w4[3];
      }
    }
    #pragma unroll
    for (int r = 0; r < 8; r++){
      float v = (t0 + r < L) ? acc[r] : 0.f;
      out[(n0 + r)*400 + e] = v;
    }
  }
}

extern "C" void kernel_launch(void* const* d_in, const int* in_sizes, int n_in,
                              void* d_out, int out_size, void* d_ws, size_t ws_size,
                              hipStream_t stream){
  const float* x1   = (const float*)d_in[0];
  const float* x2   = (const float*)d_in[1];
  // d_in[2] = cate: unused by the reference
  const int*   seq  = (const int*)d_in[3];
  const float* wihf = (const float*)d_in[4];
  const float* whhf = (const float*)d_in[5];
  const float* bihf = (const float*)d_in[6];
  const float* bhhf = (const float*)d_in[7];
  const float* wihb = (const float*)d_in[8];
  const float* whhb = (const float*)d_in[9];
  const float* bihb = (const float*)d_in[10];
  const float* bhhb = (const float*)d_in[11];
  const float* wq   = (const float*)d_in[12];
  const float* bq   = (const float*)d_in[13];
  const float* wk   = (const float*)d_in[14];
  const float* bk   = (const float*)d_in[15];
  const float* wmha = (const float*)d_in[16];
  const float* bmha = (const float*)d_in[17];
  const float* wattn= (const float*)d_in[18];
  // d_in[19] = b_attn: cancels in softmax
  const float* wmlp = (const float*)d_in[20];
  const float* bmlp = (const float*)d_in[21];
  float* out = (float*)d_out;

  char* ws = (char*)d_ws;
  u16*  wqb    = (u16*)(ws + 0);              // 320,000 B
  u16*  wkb    = (u16*)(ws + 320000);         // 320,000
  u16*  wihfb  = (u16*)(ws + 640000);         // 640,000
  u16*  wihbb  = (u16*)(ws + 1280000);        // 640,000
  signed char* w8f  = (signed char*)(ws + 1920000);  // 212,992 (4*208*256)
  signed char* w8b  = (signed char*)(ws + 2132992);  // 212,992
  float* sclf  = (float*)(ws + 2345984);      // 3,200
  float* sclb  = (float*)(ws + 2349184);      // 3,200
  float* bgf   = (float*)(ws + 2352384);      // 3,200
  float* bgb   = (float*)(ws + 2355584);      // 3,200 -> end 2,358,784
  float* pooled= (float*)(ws + 2359296);      // 13,107,200
  float* x2p   = (float*)(ws + 15466496);     // 13,107,200
  u16*  xWf    = (u16*)(ws + 28573696);       // 13,107,200
  u16*  xWb    = (u16*)(ws + 41680896);       // 13,107,200
  float* h_ws  = (float*)(ws + 54788096);     // 13,107,200 (end ~67.9MB)
  float* x1_att= (float*)(ws + 28573696);     // overlay: xWf dead after k4

  k0_cvt  <<<dim3(1250), dim3(256), 0, stream>>>(wq, wk, wihf, wihb,
                                                 bihf, bhhf, bihb, bhhb,
                                                 wqb, wkb, wihfb, wihbb, bgf, bgb);
  k0b_quant<<<dim3(416), dim3(256), 0, stream>>>(whhf, whhb, w8f, w8b, sclf, sclb);
  k1_pool <<<dim3(4096), dim3(256), 0, stream>>>(x2, wqb, bq, wkb, bk, pooled);
  k3_xw   <<<dim3(256),  dim3(512), 0, stream>>>(x1, seq, wihfb, wihbb, bgf, bgb, xWf, xWb);
  k2_x2p  <<<dim3(1024), dim3(256), 0, stream>>>(pooled, wmha, bmha, x2p);
  k4_lstm <<<dim3(4),    dim3(512), 0, stream>>>(xWf, xWb, w8f, w8b, sclf, sclb, seq, h_ws);
  k4b_fill<<<dim3(32),   dim3(256), 0, stream>>>(seq, h_ws);
  k5_attn <<<dim3(32),   dim3(512), 0, stream>>>(h_ws, wattn, x1_att);
  k6_out  <<<dim3(1024), dim3(256), 0, stream>>>(x1_att, x2p, wmlp, bmlp, seq, out);
}

// Round 8
// 1388.071 us; speedup vs baseline: 1.4545x; 1.4545x over previous
//
// NeRTModel_60997125538302 — round 8: parallelize k4 across 16 CUs + cut per-step VALU.
// r7 lesson: spill was NOT the constraint (VGPR=88, no spill, still 1095us). Counters say
// VALU-issue+latency bound on 4 CUs (per-active-CU VALUBusy ~60%). Fix: grid 4 -> 16
// (2 dir x 8 groups of 4 batch); activation cell-per-thread (1 b128 = all 4 gates);
// gates kept f32 in LDS (no f2bf repack); xW [t][b32][hu][gt] so 1x8B coalesced load/cell,
// prefetched at step top; 4 reg pairs + 20-pair LDS pool (80KB); h8 stride 288.

#include <hip/hip_runtime.h>
#include <hip/hip_bf16.h>
#include <cstdint>
#include <cstddef>

typedef unsigned short u16;
typedef __attribute__((ext_vector_type(8))) short short8v;
typedef __attribute__((ext_vector_type(4))) short short4v;
typedef __attribute__((ext_vector_type(4))) float f32x4;
typedef __attribute__((ext_vector_type(4))) int i32x4;

#define MFMA16 __builtin_amdgcn_mfma_f32_16x16x32_bf16
#define MFMAI8 __builtin_amdgcn_mfma_i32_16x16x64_i8

__device__ __forceinline__ float bf2f(u16 u){
  union { unsigned int i; float f; } v; v.i = ((unsigned int)u) << 16; return v.f;
}
__device__ __forceinline__ u16 f2bf(float f){
  union { float f; unsigned int u; } v; v.f = f;
  unsigned int r = v.u + 0x7FFFu + ((v.u >> 16) & 1u);
  return (u16)(r >> 16);
}
__device__ __forceinline__ short8v szero(){
  short8v z;
  #pragma unroll
  for (int i = 0; i < 8; i++) z[i] = 0;
  return z;
}
__device__ __forceinline__ float sigm(float x){ return 1.0f/(1.0f + __expf(-x)); }
__device__ __forceinline__ float tanh_u(float x){
  float e = __expf(2.f*x);              // overflow -> inf -> tanh -> 1 (no NaN)
  return 1.f - 2.f/(e + 1.f);
}

// ---------------- K0: convert non-recurrent weights f32 -> bf16; fuse LSTM biases ----------------
__global__ void k0_cvt(const float* __restrict__ wq, const float* __restrict__ wk,
                       const float* __restrict__ wihf, const float* __restrict__ wihb,
                       const float* __restrict__ bihf, const float* __restrict__ bhhf,
                       const float* __restrict__ bihb, const float* __restrict__ bhhb,
                       u16* __restrict__ wqb, u16* __restrict__ wkb,
                       u16* __restrict__ wihfb, u16* __restrict__ wihbb,
                       float* __restrict__ bgf, float* __restrict__ bgb){
  int i = blockIdx.x*256 + threadIdx.x;
  if (i < 160000){ wqb[i] = f2bf(wq[i]); wkb[i] = f2bf(wk[i]); }
  if (i < 320000){ wihfb[i] = f2bf(wihf[i]); wihbb[i] = f2bf(wihb[i]); }
  if (i < 800){ bgf[i] = bihf[i] + bhhf[i]; bgb[i] = bihb[i] + bhhb[i]; }
}

// ---------------- K0b: row-quantize W_hh -> i8 [4 gate][208 row][256 k] + scales ----------------
__global__ void k0b_quant(const float* __restrict__ whhf, const float* __restrict__ whhb,
                          signed char* __restrict__ w8f, signed char* __restrict__ w8b,
                          float* __restrict__ sclf, float* __restrict__ sclb){
  const int tid = threadIdx.x, lane = tid & 63, wv = tid >> 6;
  const int widx = blockIdx.x*4 + wv;              // 0..1663
  if (widx < 1600){
    int dir = widx / 800, g = widx - dir*800;
    const float* src = (dir ? whhb : whhf) + (size_t)g*200;
    float mx = 0.f;
    for (int j = lane; j < 200; j += 64) mx = fmaxf(mx, fabsf(src[j]));
    #pragma unroll
    for (int m = 32; m > 0; m >>= 1) mx = fmaxf(mx, __shfl_xor(mx, m, 64));
    float inv = (mx > 0.f) ? 127.f/mx : 0.f;
    int gt = g / 200, hl = g - gt*200;
    signed char* dst = (dir ? w8b : w8f) + (size_t)(gt*208 + hl)*256;
    int e0 = lane*4;
    unsigned int pack = 0u;
    if (e0 < 200){
      #pragma unroll
      for (int r = 0; r < 4; r++){
        int qv = __float2int_rn(src[e0+r]*inv);
        pack |= ((unsigned int)(qv & 255)) << (8*r);
      }
    }
    ((unsigned int*)dst)[lane] = pack;               // lanes 50..63 zero the k-pad
    // dequant scale for acc = sum(W_q * h_q): W ~ W_q*mx/127, h ~ h_q/127
    if (lane == 0) (dir ? sclb : sclf)[g] = mx / 16129.f;   // mx / 127^2
  } else {
    int pr = widx - 1600;                            // 64 pad rows (2 dir x 4 gt x 8)
    int dir = pr >> 5, rem = pr & 31, gt = rem >> 3, hl = 200 + (rem & 7);
    signed char* dst = (dir ? w8b : w8f) + (size_t)(gt*208 + hl)*256;
    ((unsigned int*)dst)[lane] = 0u;
  }
}

// ---------------- K1: per-news word-attention pooling (2 news per block) ----------------
__launch_bounds__(256)
__global__ void k1_pool(const float* __restrict__ x2,
                        const u16* __restrict__ wqb, const float* __restrict__ bq,
                        const u16* __restrict__ wkb, const float* __restrict__ bk,
                        float* __restrict__ pooled){
  __shared__ u16 tok[2][6400];
  __shared__ u16 qs [2][6400];
  __shared__ u16 kss[2][6400];
  __shared__ u16 probs[2][5120];
  __shared__ float msum[2][256];
  __shared__ float tval[2][16];
  __shared__ float attw[2][16];
  const int tid = threadIdx.x;
  const size_t n0 = (size_t)blockIdx.x * 2;
  const float* src = x2 + n0*6400;
  for (int i = tid; i < 3200; i += 256){
    f32x4 v = *(const f32x4*)&src[(size_t)i*4];
    short4v s; s[0]=f2bf(v[0]); s[1]=f2bf(v[1]); s[2]=f2bf(v[2]); s[3]=f2bf(v[3]);
    int j = i / 1600, r = i - j*1600;
    ((short4v*)tok[j])[r] = s;
  }
  __syncthreads();

  const int lane = tid & 63, wv = tid >> 6;
  const int q = lane & 15, kg = lane >> 4;
  {
    const int proj = wv >> 1;                 // 0: q, 1: k
    const int ntbase = (wv & 1) ? 13 : 0;
    const int ntcnt  = (wv & 1) ? 12 : 13;    // 25 col-tiles total
    const u16* W    = proj ? wkb : wqb;
    const float* bias = proj ? bk : bq;
    short8v A[2][13];
    #pragma unroll
    for (int j = 0; j < 2; j++)
      #pragma unroll
      for (int ksi = 0; ksi < 13; ksi++){
        int e0 = ksi*32 + kg*8;
        A[j][ksi] = (e0 < 400) ? *(const short8v*)&tok[j][q*400 + e0] : szero();
      }
    u16* d0 = proj ? kss[0] : qs[0];
    u16* d1 = proj ? kss[1] : qs[1];
    for (int ti = 0; ti < ntcnt; ti++){
      int col = (ntbase + ti)*16 + q;
      float bv = bias[col];
      f32x4 acc0, acc1;
      acc0[0]=bv; acc0[1]=bv; acc0[2]=bv; acc0[3]=bv; acc1 = acc0;
      const u16* wrow = W + (size_t)col*400;
      #pragma unroll
      for (int ksi = 0; ksi < 13; ksi++){
        int e0 = ksi*32 + kg*8;
        short8v bf = (e0 < 400) ? *(const short8v*)&wrow[e0] : szero();
        acc0 = MFMA16(A[0][ksi], bf, acc0, 0, 0, 0);
        acc1 = MFMA16(A[1][ksi], bf, acc1, 0, 0, 0);
      }
      #pragma unroll
      for (int r = 0; r < 4; r++){          // D: row=(l>>4)*4+r, col=l&15
        d0[(kg*4+r)*400 + col] = f2bf(acc0[r]);
        d1[(kg*4+r)*400 + col] = f2bf(acc1[r]);
      }
    }
  }
  __syncthreads();
  // scores per (news, head, sq): dot20 over head dims, softmax over sk
  for (int r0 = tid; r0 < 640; r0 += 256){
    int j = r0 / 320, rem = r0 - j*320;
    int hh = rem >> 4, sq = rem & 15;
    const u16* qrow = &qs[j][sq*400 + hh*20];
    float qv[20];
    #pragma unroll
    for (int d5 = 0; d5 < 5; d5++){
      short4v v = *(const short4v*)&qrow[d5*4];
      qv[d5*4+0]=bf2f((u16)v[0]); qv[d5*4+1]=bf2f((u16)v[1]);
      qv[d5*4+2]=bf2f((u16)v[2]); qv[d5*4+3]=bf2f((u16)v[3]);
    }
    float sc[16]; float mx = -1e30f;
    #pragma unroll
    for (int sk = 0; sk < 16; sk++){
      const u16* krow = &kss[j][sk*400 + hh*20];
      float s = 0.f;
      #pragma unroll
      for (int d5 = 0; d5 < 5; d5++){
        short4v v = *(const short4v*)&krow[d5*4];
        s += qv[d5*4+0]*bf2f((u16)v[0]) + qv[d5*4+1]*bf2f((u16)v[1])
           + qv[d5*4+2]*bf2f((u16)v[2]) + qv[d5*4+3]*bf2f((u16)v[3]);
      }
      s *= 0.22360679775f;                   // 1/sqrt(20)
      sc[sk] = s; mx = fmaxf(mx, s);
    }
    float sum = 0.f;
    #pragma unroll
    for (int sk = 0; sk < 16; sk++){ sc[sk] = __expf(sc[sk]-mx); sum += sc[sk]; }
    float inv = 1.f/sum;
    #pragma unroll
    for (int sk = 0; sk < 16; sk++) probs[j][(hh*16+sq)*16 + sk] = f2bf(sc[sk]*inv);
  }
  __syncthreads();
  #pragma unroll
  for (int it = 0; it < 2; it++){            // mean over heads
    int idx = tid + it*256;
    int j = idx >> 8, sq = (idx >> 4) & 15, sk = idx & 15;
    float s = 0.f;
    #pragma unroll
    for (int hh = 0; hh < 20; hh++) s += bf2f(probs[j][(hh*16+sq)*16 + sk]);
    msum[j][sq*16+sk] = s * 0.05f;
  }
  __syncthreads();
  if (tid < 32){                             // mean over sk
    int j = tid >> 4, sq = tid & 15;
    float s = 0.f;
    #pragma unroll
    for (int sk = 0; sk < 16; sk++) s += msum[j][sq*16+sk];
    tval[j][sq] = s * 0.0625f;
  }
  __syncthreads();
  if (tid < 2){                              // softmax over sq (16 values)
    float mx = -1e30f;
    for (int i = 0; i < 16; i++) mx = fmaxf(mx, tval[tid][i]);
    float sum = 0.f; float ev[16];
    for (int i = 0; i < 16; i++){ ev[i] = __expf(tval[tid][i]-mx); sum += ev[i]; }
    float inv = 1.f/sum;
    for (int i = 0; i < 16; i++) attw[tid][i] = ev[i]*inv;
  }
  __syncthreads();
  for (int e = tid; e < 800; e += 256){
    int j = e / 400, c = e - j*400;
    float acc = 0.f;
    #pragma unroll
    for (int s = 0; s < 16; s++) acc += attw[j][s]*bf2f(tok[j][s*400 + c]);
    pooled[(n0+j)*400 + c] = acc;
  }
}

// ---------------- K2: x2p = pooled @ w_mlp_mha^T + b (f32 VALU) ----------------
__global__ void k2_x2p(const float* __restrict__ pooled, const float* __restrict__ wmha,
                       const float* __restrict__ bmha, float* __restrict__ x2p){
  __shared__ float rows[3200];
  const int tid = threadIdx.x;
  const size_t n0 = (size_t)blockIdx.x*8;
  for (int i = tid; i < 3200; i += 256) rows[i] = pooled[n0*400 + i];
  __syncthreads();
  for (int j = tid; j < 400; j += 256){
    float bv = bmha[j];
    float acc[8];
    #pragma unroll
    for (int r = 0; r < 8; r++) acc[r] = bv;
    const float* wr = wmha + (size_t)j*400;
    for (int e = 0; e < 400; e += 4){
      const f32x4 w4 = *(const f32x4*)&wr[e];
      #pragma unroll
      for (int r = 0; r < 8; r++){
        const f32x4 x4 = *(const f32x4*)&rows[r*400 + e];
        acc[r] += x4[0]*w4[0] + x4[1]*w4[1] + x4[2]*w4[2] + x4[3]*w4[3];
      }
    }
    #pragma unroll
    for (int r = 0; r < 8; r++) x2p[(n0+r)*400 + j] = acc[r];
  }
}

// ---------------- K3: xW = x @ W_ih^T + (b_ih+b_hh), layout [t][b32][hu][gt] bf16 ----------------
__launch_bounds__(512)
__global__ void k3_xw(const float* __restrict__ x1, const int* __restrict__ seq,
                      const u16* __restrict__ wihfb, const u16* __restrict__ wihbb,
                      const float* __restrict__ bgf, const float* __restrict__ bgb,
                      u16* __restrict__ xWf, u16* __restrict__ xWb){
  __shared__ u16 xf[12800];
  __shared__ u16 xb[12800];
  const int tid = threadIdx.x;
  const int t = blockIdx.x;
  for (int i = tid; i < 3200; i += 512){
    int b = i / 100, e4 = i - b*100;
    f32x4 vf = *(const f32x4*)&x1[((size_t)b*256 + t)*400 + e4*4];
    int rb = seq[b] - 1 - t; if (rb < 0) rb = 0;     // clip(L-1-t, 0, T-1)
    f32x4 vb = *(const f32x4*)&x1[((size_t)b*256 + rb)*400 + e4*4];
    short4v sf, sb;
    #pragma unroll
    for (int r = 0; r < 4; r++){ sf[r] = f2bf(vf[r]); sb[r] = f2bf(vb[r]); }
    ((short4v*)xf)[i] = sf;
    ((short4v*)xb)[i] = sb;
  }
  __syncthreads();
  const int lane = tid & 63, wv = tid >> 6;
  const int dir = wv >> 2, wl = wv & 3;
  const u16* xs = dir ? xb : xf;
  const u16* W  = dir ? wihbb : wihfb;
  const float* bg = dir ? bgb : bgf;
  u16* xW = dir ? xWb : xWf;
  const int q = lane & 15, kg = lane >> 4;
  short8v A[2][13];
  #pragma unroll
  for (int mt = 0; mt < 2; mt++)
    #pragma unroll
    for (int ksi = 0; ksi < 13; ksi++){
      int e0 = ksi*32 + kg*8;
      A[mt][ksi] = (e0 < 400) ? *(const short8v*)&xs[(mt*16 + q)*400 + e0] : szero();
    }
  for (int nt = wl; nt < 50; nt += 4){
    int g = nt*16 + q;                       // gate row 0..799 (i,f,g,o blocks of 200)
    float bv = bg[g];
    f32x4 acc0, acc1;
    acc0[0]=bv; acc0[1]=bv; acc0[2]=bv; acc0[3]=bv; acc1 = acc0;
    const u16* wrow = W + (size_t)g*400;
    #pragma unroll
    for (int ksi = 0; ksi < 13; ksi++){
      int e0 = ksi*32 + kg*8;
      short8v bf = (e0 < 400) ? *(const short8v*)&wrow[e0] : szero();
      acc0 = MFMA16(A[0][ksi], bf, acc0, 0,0,0);
      acc1 = MFMA16(A[1][ksi], bf, acc1, 0,0,0);
    }
    int gt = g / 200, hu = g - gt*200;
    #pragma unroll
    for (int r = 0; r < 4; r++){
      int bl = kg*4 + r;                     // D rows = batch rows
      xW[(((size_t)t*32 +      bl)*200 + hu)*4 + gt] = f2bf(acc0[r]);
      xW[(((size_t)t*32 + 16 + bl)*200 + hu)*4 + gt] = f2bf(acc1[r]);
    }
  }
}

// ---------------- K4: sequential BiLSTM, i8 MFMA. grid 16 = (dir2, grp8 of 4 batch). ----------------
__device__ __forceinline__ void store_gate_f32(int p, const i32x4& acc, int q, int kg,
                                               float* gates, const float* scl_s){
  int gt = p/13, nt = p - gt*13;
  int hu0 = nt*16 + kg*4;
  if (hu0 < 200 && q < 4){
    const f32x4 s4 = *(const f32x4*)&scl_s[gt*200 + hu0];
    #pragma unroll
    for (int r = 0; r < 4; r++)
      gates[q*804 + (hu0+r)*4 + gt] = (float)acc[r]*s4[r];
  }
}

__launch_bounds__(512)
__global__ void k4_lstm(const u16* __restrict__ xWf, const u16* __restrict__ xWb,
                        const signed char* __restrict__ w8f, const signed char* __restrict__ w8b,
                        const float* __restrict__ sclf, const float* __restrict__ sclb,
                        const int* __restrict__ seq, float* __restrict__ h_ws){
  __shared__ __align__(16) signed char h8[16*288];   // h_{t-1} i8; rows 4..15 stay zero
  __shared__ __align__(16) float gates[4*804];       // [b4][hu*4+gt], b-stride 804 words
  __shared__ __align__(16) i32x4 pool[20*4*64];      // pairs 32..51 fragment pool (80KB)
  __shared__ float scl_s[800];
  __shared__ int Ls[4];
  const int tid = threadIdx.x;
  const int dir = blockIdx.x >> 3, grp = blockIdx.x & 7;
  const u16* xWd = dir ? xWb : xWf;
  const signed char* w8 = dir ? w8b : w8f;
  const float* scl = dir ? sclb : sclf;
  if (tid < 4) Ls[tid] = seq[grp*4 + tid];
  for (int i = tid; i < 1152; i += 512) ((int*)h8)[i] = 0;
  for (int i = tid; i < 800; i += 512) scl_s[i] = scl[i];
  const int lane = tid & 63, wv = tid >> 6;
  const int q = lane & 15, kg = lane >> 4;
  // pool fill: slot s holds pair p = 32+s (fragment order -> conflict-free b128 reads)
  for (int idx = tid; idx < 20*4*64; idx += 512){
    int s = idx >> 8, rem = idx & 255;
    int ksi = rem >> 6, l = rem & 63;
    int qq = l & 15, kk = l >> 4;
    int p = 32 + s, gt = p/13, nt = p - gt*13;
    pool[idx] = *(const i32x4*)&w8[(size_t)(gt*208 + nt*16 + qq)*256 + ksi*64 + kk*16];
  }
  // register pairs p = wv + 8j, j<4 (64 VGPR)
  i32x4 Wr[4][4];
  #pragma unroll
  for (int j = 0; j < 4; j++){
    int p = wv + 8*j, gt = p/13, nt = p - gt*13;
    #pragma unroll
    for (int ksi = 0; ksi < 4; ksi++)
      Wr[j][ksi] = *(const i32x4*)&w8[(size_t)(gt*208 + nt*16 + q)*256 + ksi*64 + kg*16];
  }
  float cst0 = 0.f, cst1 = 0.f;
  // cell mapping: cell = b*200 + hu over 4 local batches
  const int c0 = tid,        b0c = c0/200, hu0c = c0 - b0c*200;      // always valid
  const int c1 = tid + 512,  b1c = c1/200, hu1c = c1 - b1c*200;      // valid if tid<288
  const int xoff0 = ((grp*4 + b0c)*200 + hu0c)*4;
  const int xoff1 = ((grp*4 + b1c)*200 + hu1c)*4;
  __syncthreads();
  #pragma unroll 1
  for (int t = 0; t < 256; t++){
    // prefetch this step's xW (hides under the MFMA phase)
    const u16* xwt = xWd + (size_t)t*25600;
    short4v xwv0 = *(const short4v*)&xwt[xoff0];
    short4v xwv1; if (tid < 288) xwv1 = *(const short4v*)&xwt[xoff1];
    // h_{t-1} B-fragments
    i32x4 bh[4];
    #pragma unroll
    for (int ksi = 0; ksi < 4; ksi++)
      bh[ksi] = *(const i32x4*)&h8[q*288 + ksi*64 + kg*16];
    // 4 register pairs
    #pragma unroll
    for (int j = 0; j < 4; j++){
      i32x4 acc = {0,0,0,0};
      #pragma unroll
      for (int ksi = 0; ksi < 4; ksi++)
        acc = MFMAI8(Wr[j][ksi], bh[ksi], acc, 0,0,0);
      store_gate_f32(wv + 8*j, acc, q, kg, gates, scl_s);
    }
    // 2 pool pairs (all waves)
    #pragma unroll
    for (int jp = 0; jp < 2; jp++){
      int s = wv + 8*jp;
      i32x4 acc = {0,0,0,0};
      #pragma unroll
      for (int ksi = 0; ksi < 4; ksi++)
        acc = MFMAI8(pool[(s*4 + ksi)*64 + lane], bh[ksi], acc, 0,0,0);
      store_gate_f32(32 + s, acc, q, kg, gates, scl_s);
    }
    // 4 leftover pool pairs on waves 0..3
    if (wv < 4){
      int s = 16 + wv;
      i32x4 acc = {0,0,0,0};
      #pragma unroll
      for (int ksi = 0; ksi < 4; ksi++)
        acc = MFMAI8(pool[(s*4 + ksi)*64 + lane], bh[ksi], acc, 0,0,0);
      store_gate_f32(32 + s, acc, q, kg, gates, scl_s);
    }
    __syncthreads();                               // gates ready
    // activation: 1 cell per thread (2nd cell for tid<288); 1 b128 = all 4 gates
    {
      const f32x4 g4 = *(const f32x4*)&gates[b0c*804 + hu0c*4];
      float gi = g4[0] + bf2f((u16)xwv0[0]);
      float gf = g4[1] + bf2f((u16)xwv0[1]);
      float gg = g4[2] + bf2f((u16)xwv0[2]);
      float go = g4[3] + bf2f((u16)xwv0[3]);
      float c = sigm(gf)*cst0 + sigm(gi)*tanh_u(gg);
      cst0 = c;
      float hv = sigm(go)*tanh_u(c);
      h8[b0c*288 + hu0c] = (signed char)__float2int_rn(hv*127.f);
      int gb = grp*4 + b0c;
      if (dir == 0){
        h_ws[((size_t)gb*256 + t)*400 + hu0c] = hv;
      } else {
        int tp = Ls[b0c] - 1 - t;
        if (tp >= 0) h_ws[((size_t)gb*256 + tp)*400 + 200 + hu0c] = hv;
      }
    }
    if (tid < 288){
      const f32x4 g4 = *(const f32x4*)&gates[b1c*804 + hu1c*4];
      float gi = g4[0] + bf2f((u16)xwv1[0]);
      float gf = g4[1] + bf2f((u16)xwv1[1]);
      float gg = g4[2] + bf2f((u16)xwv1[2]);
      float go = g4[3] + bf2f((u16)xwv1[3]);
      float c = sigm(gf)*cst1 + sigm(gi)*tanh_u(gg);
      cst1 = c;
      float hv = sigm(go)*tanh_u(c);
      h8[b1c*288 + hu1c] = (signed char)__float2int_rn(hv*127.f);
      int gb = grp*4 + b1c;
      if (dir == 0){
        h_ws[((size_t)gb*256 + t)*400 + hu1c] = hv;
      } else {
        int tp = Ls[b1c] - 1 - t;
        if (tp >= 0) h_ws[((size_t)gb*256 + tp)*400 + 200 + hu1c] = hv;
      }
    }
    __syncthreads();                               // h8 ready for t+1
  }
}

// ---------------- K4b: fill bwd rows t>=L with h_bwd_r[0] (== stored row L-1) ----------------
__global__ void k4b_fill(const int* __restrict__ seq, float* __restrict__ h_ws){
  const int b = blockIdx.x;
  const int L = seq[b];
  const int cnt = (256 - L)*200;
  const float* src = h_ws + ((size_t)b*256 + (L-1))*400 + 200;
  for (int i = threadIdx.x; i < cnt; i += 256){
    int tt = L + i/200, cc = i - (i/200)*200;
    h_ws[((size_t)b*256 + tt)*400 + 200 + cc] = src[cc];
  }
}

// ---------------- K5: causal growing-window attention (query term cancels) ----------------
__launch_bounds__(512)
__global__ void k5_attn(const float* __restrict__ h_ws, const float* __restrict__ wattn,
                        float* __restrict__ x1_att){
  __shared__ float a_lds[256];
  const int tid = threadIdx.x;
  const int b = blockIdx.x;
  const int lane = tid & 63, wv = tid >> 6;
  for (int row = wv*32; row < wv*32 + 32; row++){
    float s = 0.f;
    for (int j = lane; j < 400; j += 64)
      s += h_ws[((size_t)b*256 + row)*400 + j] * wattn[j];
    #pragma unroll
    for (int m = 32; m > 0; m >>= 1) s += __shfl_xor(s, m, 64);
    if (lane == 0) a_lds[row] = s;
  }
  __syncthreads();
  const int col = tid;
  const bool act = col < 400;
  float m = -1e30f, den = 0.f, num = 0.f;
  const float* hb = h_ws + (size_t)b*256*400 + col;
  float* ob = x1_att + (size_t)b*256*400 + col;
  float hvA = act ? hb[0] : 0.f;
  float hvB = act ? hb[400] : 0.f;
  for (int t = 0; t < 256; t++){
    float hv = hvA; hvA = hvB;
    hvB = (act && t + 2 < 256) ? hb[(size_t)(t+2)*400] : 0.f;
    float at = a_lds[t];
    float mn = fmaxf(m, at);
    float rr  = __expf(m - mn);
    float wgt = __expf(at - mn);
    den = den*rr + wgt;
    num = num*rr + wgt*hv;
    m = mn;
    if (act) ob[(size_t)t*400] = num/den;
  }
}

// ---------------- K6: out = [x1_att ; x2p] @ w_mlp^T + b, masked, f32 ----------------
__global__ void k6_out(const float* __restrict__ x1_att, const float* __restrict__ x2p,
                       const float* __restrict__ wmlp, const float* __restrict__ bmlp,
                       const int* __restrict__ seq, float* __restrict__ out){
  __shared__ float rows[8*800];
  const int tid = threadIdx.x;
  const size_t n0 = (size_t)blockIdx.x*8;
  const int b = (int)(n0 >> 8), t0 = (int)(n0 & 255);
  const int L = seq[b];
  for (int i = tid; i < 3200; i += 256){
    int r = i / 400, e = i - r*400;
    rows[r*800 + e]       = x1_att[(n0 + r)*400 + e];
    rows[r*800 + 400 + e] = x2p  [(n0 + r)*400 + e];
  }
  __syncthreads();
  for (int e = tid; e < 400; e += 256){
    float bv = bmlp[e];
    float acc[8];
    #pragma unroll
    for (int r = 0; r < 8; r++) acc[r] = bv;
    const float* wr = wmlp + (size_t)e*800;
    for (int j = 0; j < 800; j += 4){
      const f32x4 w4 = *(const f32x4*)&wr[j];
      #pragma unroll
      for (int r = 0; r < 8; r++){
        const f32x4 x4 = *(const f32x4*)&rows[r*800 + j];
        acc[r] += x4[0]*w4[0] + x4[1]*w4[1] + x4[2]*w4[2] + x4[3]*w4[3];
      }
    }
    #pragma unroll
    for (int r = 0; r < 8; r++){
      float v = (t0 + r < L) ? acc[r] : 0.f;
      out[(n0 + r)*400 + e] = v;
    }
  }
}

extern "C" void kernel_launch(void* const* d_in, const int* in_sizes, int n_in,
                              void* d_out, int out_size, void* d_ws, size_t ws_size,
                              hipStream_t stream){
  const float* x1   = (const float*)d_in[0];
  const float* x2   = (const float*)d_in[1];
  // d_in[2] = cate: unused by the reference
  const int*   seq  = (const int*)d_in[3];
  const float* wihf = (const float*)d_in[4];
  const float* whhf = (const float*)d_in[5];
  const float* bihf = (const float*)d_in[6];
  const float* bhhf = (const float*)d_in[7];
  const float* wihb = (const float*)d_in[8];
  const float* whhb = (const float*)d_in[9];
  const float* bihb = (const float*)d_in[10];
  const float* bhhb = (const float*)d_in[11];
  const float* wq   = (const float*)d_in[12];
  const float* bq   = (const float*)d_in[13];
  const float* wk   = (const float*)d_in[14];
  const float* bk   = (const float*)d_in[15];
  const float* wmha = (const float*)d_in[16];
  const float* bmha = (const float*)d_in[17];
  const float* wattn= (const float*)d_in[18];
  // d_in[19] = b_attn: cancels in softmax
  const float* wmlp = (const float*)d_in[20];
  const float* bmlp = (const float*)d_in[21];
  float* out = (float*)d_out;

  char* ws = (char*)d_ws;
  u16*  wqb    = (u16*)(ws + 0);              // 320,000 B
  u16*  wkb    = (u16*)(ws + 320000);         // 320,000
  u16*  wihfb  = (u16*)(ws + 640000);         // 640,000
  u16*  wihbb  = (u16*)(ws + 1280000);        // 640,000
  signed char* w8f  = (signed char*)(ws + 1920000);  // 212,992 (4*208*256)
  signed char* w8b  = (signed char*)(ws + 2132992);  // 212,992
  float* sclf  = (float*)(ws + 2345984);      // 3,200
  float* sclb  = (float*)(ws + 2349184);      // 3,200
  float* bgf   = (float*)(ws + 2352384);      // 3,200
  float* bgb   = (float*)(ws + 2355584);      // 3,200 -> end 2,358,784
  float* pooled= (float*)(ws + 2359296);      // 13,107,200
  float* x2p   = (float*)(ws + 15466496);     // 13,107,200
  u16*  xWf    = (u16*)(ws + 28573696);       // 13,107,200
  u16*  xWb    = (u16*)(ws + 41680896);       // 13,107,200
  float* h_ws  = (float*)(ws + 54788096);     // 13,107,200 (end ~67.9MB)
  float* x1_att= (float*)(ws + 28573696);     // overlay: xWf dead after k4

  k0_cvt  <<<dim3(1250), dim3(256), 0, stream>>>(wq, wk, wihf, wihb,
                                                 bihf, bhhf, bihb, bhhb,
                                                 wqb, wkb, wihfb, wihbb, bgf, bgb);
  k0b_quant<<<dim3(416), dim3(256), 0, stream>>>(whhf, whhb, w8f, w8b, sclf, sclb);
  k1_pool <<<dim3(4096), dim3(256), 0, stream>>>(x2, wqb, bq, wkb, bk, pooled);
  k3_xw   <<<dim3(256),  dim3(512), 0, stream>>>(x1, seq, wihfb, wihbb, bgf, bgb, xWf, xWb);
  k2_x2p  <<<dim3(1024), dim3(256), 0, stream>>>(pooled, wmha, bmha, x2p);
  k4_lstm <<<dim3(16),   dim3(512), 0, stream>>>(xWf, xWb, w8f, w8b, sclf, sclb, seq, h_ws);
  k4b_fill<<<dim3(32),   dim3(256), 0, stream>>>(seq, h_ws);
  k5_attn <<<dim3(32),   dim3(512), 0, stream>>>(h_ws, wattn, x1_att);
  k6_out  <<<dim3(1024), dim3(256), 0, stream>>>(x1_att, x2p, wmlp, bmlp, seq, out);
}

// Round 9
// 1305.064 us; speedup vs baseline: 1.5470x; 1.0636x over previous
//
// NeRTModel_60997125538302 — round 9: k1 occupancy+conflict fix, k5 coalescing fix.
// k1 (538us, 39%): LDS 99.8KB forced 1 wave/SIMD (Occ 12%) + 6.1M bank conflicts in the
// score phase (800B row stride -> bank stride 8). Fix: drop probs buffer (head-mean via
// shfl pre-reduce + LDS atomicAdd), q/k stride 404 (bank-spread, b64-aligned) -> LDS
// 79.6KB -> 2 blocks/CU; score k-reads are lane-broadcast.
// k5: column-strided h/x1_att access was 16x overfetch; now 32-row LDS tiles, coalesced
// load/flush, scan from LDS. k0/k0b/k2/k3/k4/k4b/k6 identical to round 8.

#include <hip/hip_runtime.h>
#include <hip/hip_bf16.h>
#include <cstdint>
#include <cstddef>

typedef unsigned short u16;
typedef __attribute__((ext_vector_type(8))) short short8v;
typedef __attribute__((ext_vector_type(4))) short short4v;
typedef __attribute__((ext_vector_type(4))) float f32x4;
typedef __attribute__((ext_vector_type(4))) int i32x4;

#define MFMA16 __builtin_amdgcn_mfma_f32_16x16x32_bf16
#define MFMAI8 __builtin_amdgcn_mfma_i32_16x16x64_i8

__device__ __forceinline__ float bf2f(u16 u){
  union { unsigned int i; float f; } v; v.i = ((unsigned int)u) << 16; return v.f;
}
__device__ __forceinline__ u16 f2bf(float f){
  union { float f; unsigned int u; } v; v.f = f;
  unsigned int r = v.u + 0x7FFFu + ((v.u >> 16) & 1u);
  return (u16)(r >> 16);
}
__device__ __forceinline__ short8v szero(){
  short8v z;
  #pragma unroll
  for (int i = 0; i < 8; i++) z[i] = 0;
  return z;
}
__device__ __forceinline__ float sigm(float x){ return 1.0f/(1.0f + __expf(-x)); }
__device__ __forceinline__ float tanh_u(float x){
  float e = __expf(2.f*x);              // overflow -> inf -> tanh -> 1 (no NaN)
  return 1.f - 2.f/(e + 1.f);
}

// ---------------- K0: convert non-recurrent weights f32 -> bf16; fuse LSTM biases ----------------
__global__ void k0_cvt(const float* __restrict__ wq, const float* __restrict__ wk,
                       const float* __restrict__ wihf, const float* __restrict__ wihb,
                       const float* __restrict__ bihf, const float* __restrict__ bhhf,
                       const float* __restrict__ bihb, const float* __restrict__ bhhb,
                       u16* __restrict__ wqb, u16* __restrict__ wkb,
                       u16* __restrict__ wihfb, u16* __restrict__ wihbb,
                       float* __restrict__ bgf, float* __restrict__ bgb){
  int i = blockIdx.x*256 + threadIdx.x;
  if (i < 160000){ wqb[i] = f2bf(wq[i]); wkb[i] = f2bf(wk[i]); }
  if (i < 320000){ wihfb[i] = f2bf(wihf[i]); wihbb[i] = f2bf(wihb[i]); }
  if (i < 800){ bgf[i] = bihf[i] + bhhf[i]; bgb[i] = bihb[i] + bhhb[i]; }
}

// ---------------- K0b: row-quantize W_hh -> i8 [4 gate][208 row][256 k] + scales ----------------
__global__ void k0b_quant(const float* __restrict__ whhf, const float* __restrict__ whhb,
                          signed char* __restrict__ w8f, signed char* __restrict__ w8b,
                          float* __restrict__ sclf, float* __restrict__ sclb){
  const int tid = threadIdx.x, lane = tid & 63, wv = tid >> 6;
  const int widx = blockIdx.x*4 + wv;              // 0..1663
  if (widx < 1600){
    int dir = widx / 800, g = widx - dir*800;
    const float* src = (dir ? whhb : whhf) + (size_t)g*200;
    float mx = 0.f;
    for (int j = lane; j < 200; j += 64) mx = fmaxf(mx, fabsf(src[j]));
    #pragma unroll
    for (int m = 32; m > 0; m >>= 1) mx = fmaxf(mx, __shfl_xor(mx, m, 64));
    float inv = (mx > 0.f) ? 127.f/mx : 0.f;
    int gt = g / 200, hl = g - gt*200;
    signed char* dst = (dir ? w8b : w8f) + (size_t)(gt*208 + hl)*256;
    int e0 = lane*4;
    unsigned int pack = 0u;
    if (e0 < 200){
      #pragma unroll
      for (int r = 0; r < 4; r++){
        int qv = __float2int_rn(src[e0+r]*inv);
        pack |= ((unsigned int)(qv & 255)) << (8*r);
      }
    }
    ((unsigned int*)dst)[lane] = pack;               // lanes 50..63 zero the k-pad
    // dequant scale for acc = sum(W_q * h_q): W ~ W_q*mx/127, h ~ h_q/127
    if (lane == 0) (dir ? sclb : sclf)[g] = mx / 16129.f;   // mx / 127^2
  } else {
    int pr = widx - 1600;                            // 64 pad rows (2 dir x 4 gt x 8)
    int dir = pr >> 5, rem = pr & 31, gt = rem >> 3, hl = 200 + (rem & 7);
    signed char* dst = (dir ? w8b : w8f) + (size_t)(gt*208 + hl)*256;
    ((unsigned int*)dst)[lane] = 0u;
  }
}

// ---------------- K1: per-news word-attention pooling (2 news per block) ----------------
// LDS 79.6KB -> 2 blocks/CU. q/k stride 404 u16 (bank-spread). Head-mean via shfl+atomicAdd.
__launch_bounds__(256)
__global__ void k1_pool(const float* __restrict__ x2,
                        const u16* __restrict__ wqb, const float* __restrict__ bq,
                        const u16* __restrict__ wkb, const float* __restrict__ bk,
                        float* __restrict__ pooled){
  __shared__ u16 tok[2][6400];          // 25,600 B
  __shared__ u16 qs [2][16*404];        // 25,856 B (stride 404)
  __shared__ u16 kss[2][16*404];        // 25,856 B
  __shared__ float msum[2][256];        // 2,048 B [j][sq*16+sk]
  __shared__ float tval[2][16];
  __shared__ float attw[2][16];
  const int tid = threadIdx.x;
  const size_t n0 = (size_t)blockIdx.x * 2;
  const float* src = x2 + n0*6400;
  for (int i = tid; i < 512; i += 256) ((float*)msum)[i] = 0.f;
  for (int i = tid; i < 3200; i += 256){
    f32x4 v = *(const f32x4*)&src[(size_t)i*4];
    short4v s; s[0]=f2bf(v[0]); s[1]=f2bf(v[1]); s[2]=f2bf(v[2]); s[3]=f2bf(v[3]);
    int j = i / 1600, r = i - j*1600;
    ((short4v*)tok[j])[r] = s;
  }
  __syncthreads();

  const int lane = tid & 63, wv = tid >> 6;
  const int q = lane & 15, kg = lane >> 4;
  {
    const int proj = wv >> 1;                 // 0: q, 1: k
    const int ntbase = (wv & 1) ? 13 : 0;
    const int ntcnt  = (wv & 1) ? 12 : 13;    // 25 col-tiles total
    const u16* W    = proj ? wkb : wqb;
    const float* bias = proj ? bk : bq;
    short8v A[2][13];
    #pragma unroll
    for (int j = 0; j < 2; j++)
      #pragma unroll
      for (int ksi = 0; ksi < 13; ksi++){
        int e0 = ksi*32 + kg*8;
        A[j][ksi] = (e0 < 400) ? *(const short8v*)&tok[j][q*400 + e0] : szero();
      }
    u16* d0 = proj ? kss[0] : qs[0];
    u16* d1 = proj ? kss[1] : qs[1];
    for (int ti = 0; ti < ntcnt; ti++){
      int col = (ntbase + ti)*16 + q;
      float bv = bias[col];
      f32x4 acc0, acc1;
      acc0[0]=bv; acc0[1]=bv; acc0[2]=bv; acc0[3]=bv; acc1 = acc0;
      const u16* wrow = W + (size_t)col*400;
      #pragma unroll
      for (int ksi = 0; ksi < 13; ksi++){
        int e0 = ksi*32 + kg*8;
        short8v bf = (e0 < 400) ? *(const short8v*)&wrow[e0] : szero();
        acc0 = MFMA16(A[0][ksi], bf, acc0, 0, 0, 0);
        acc1 = MFMA16(A[1][ksi], bf, acc1, 0, 0, 0);
      }
      #pragma unroll
      for (int r = 0; r < 4; r++){          // D: row=(l>>4)*4+r, col=l&15
        d0[(kg*4+r)*404 + col] = f2bf(acc0[r]);
        d1[(kg*4+r)*404 + col] = f2bf(acc1[r]);
      }
    }
  }
  __syncthreads();
  // score rows (j,hh,sq): lanes 0-15 share (j,hh) -> k reads broadcast; q stride 404 spread.
  // softmax over sk in-register; head-mean: shfl over the wave's 4 hh, then one atomicAdd.
  for (int rr = 0; rr < 3; rr++){
    int row = tid + rr*256;
    if (row < 640){                          // wave-uniform (640 = 10 waves' worth)
      int j = row / 320, r2 = row - j*320;
      int hh = r2 >> 4, sq = r2 & 15;
      const u16* qrow = &qs[j][sq*404 + hh*20];
      float qv[20];
      #pragma unroll
      for (int d5 = 0; d5 < 5; d5++){
        short4v v = *(const short4v*)&qrow[d5*4];
        qv[d5*4+0]=bf2f((u16)v[0]); qv[d5*4+1]=bf2f((u16)v[1]);
        qv[d5*4+2]=bf2f((u16)v[2]); qv[d5*4+3]=bf2f((u16)v[3]);
      }
      float sc[16]; float mx = -1e30f;
      const u16* kbase = &kss[j][hh*20];
      #pragma unroll
      for (int sk = 0; sk < 16; sk++){
        const u16* krow = kbase + sk*404;
        float s = 0.f;
        #pragma unroll
        for (int d5 = 0; d5 < 5; d5++){
          short4v v = *(const short4v*)&krow[d5*4];
          s += qv[d5*4+0]*bf2f((u16)v[0]) + qv[d5*4+1]*bf2f((u16)v[1])
             + qv[d5*4+2]*bf2f((u16)v[2]) + qv[d5*4+3]*bf2f((u16)v[3]);
        }
        s *= 0.22360679775f;                 // 1/sqrt(20)
        sc[sk] = s; mx = fmaxf(mx, s);
      }
      float sum = 0.f;
      #pragma unroll
      for (int sk = 0; sk < 16; sk++){ sc[sk] = __expf(sc[sk]-mx); sum += sc[sk]; }
      float inv = 0.05f/sum;                 // fold the 1/20 head-mean in
      #pragma unroll
      for (int sk = 0; sk < 16; sk++){
        float v = sc[sk]*inv;
        v += __shfl_xor(v, 16, 64);          // sum the wave's 4 hh values
        v += __shfl_xor(v, 32, 64);
        if (kg == 0) atomicAdd(&msum[j][sq*16 + sk], v);
      }
    }
  }
  __syncthreads();
  if (tid < 32){                             // mean over sk
    int j = tid >> 4, sq = tid & 15;
    float s = 0.f;
    #pragma unroll
    for (int sk = 0; sk < 16; sk++) s += msum[j][sq*16+sk];
    tval[j][sq] = s * 0.0625f;
  }
  __syncthreads();
  if (tid < 2){                              // softmax over sq (16 values)
    float mx = -1e30f;
    for (int i = 0; i < 16; i++) mx = fmaxf(mx, tval[tid][i]);
    float sum = 0.f; float ev[16];
    for (int i = 0; i < 16; i++){ ev[i] = __expf(tval[tid][i]-mx); sum += ev[i]; }
    float inv = 1.f/sum;
    for (int i = 0; i < 16; i++) attw[tid][i] = ev[i]*inv;
  }
  __syncthreads();
  for (int e = tid; e < 800; e += 256){
    int j = e / 400, c = e - j*400;
    float acc = 0.f;
    #pragma unroll
    for (int s = 0; s < 16; s++) acc += attw[j][s]*bf2f(tok[j][s*400 + c]);
    pooled[(n0+j)*400 + c] = acc;
  }
}

// ---------------- K2: x2p = pooled @ w_mlp_mha^T + b (f32 VALU) ----------------
__global__ void k2_x2p(const float* __restrict__ pooled, const float* __restrict__ wmha,
                       const float* __restrict__ bmha, float* __restrict__ x2p){
  __shared__ float rows[3200];
  const int tid = threadIdx.x;
  const size_t n0 = (size_t)blockIdx.x*8;
  for (int i = tid; i < 3200; i += 256) rows[i] = pooled[n0*400 + i];
  __syncthreads();
  for (int j = tid; j < 400; j += 256){
    float bv = bmha[j];
    float acc[8];
    #pragma unroll
    for (int r = 0; r < 8; r++) acc[r] = bv;
    const float* wr = wmha + (size_t)j*400;
    for (int e = 0; e < 400; e += 4){
      const f32x4 w4 = *(const f32x4*)&wr[e];
      #pragma unroll
      for (int r = 0; r < 8; r++){
        const f32x4 x4 = *(const f32x4*)&rows[r*400 + e];
        acc[r] += x4[0]*w4[0] + x4[1]*w4[1] + x4[2]*w4[2] + x4[3]*w4[3];
      }
    }
    #pragma unroll
    for (int r = 0; r < 8; r++) x2p[(n0+r)*400 + j] = acc[r];
  }
}

// ---------------- K3: xW = x @ W_ih^T + (b_ih+b_hh), layout [t][b32][hu][gt] bf16 ----------------
__launch_bounds__(512)
__global__ void k3_xw(const float* __restrict__ x1, const int* __restrict__ seq,
                      const u16* __restrict__ wihfb, const u16* __restrict__ wihbb,
                      const float* __restrict__ bgf, const float* __restrict__ bgb,
                      u16* __restrict__ xWf, u16* __restrict__ xWb){
  __shared__ u16 xf[12800];
  __shared__ u16 xb[12800];
  const int tid = threadIdx.x;
  const int t = blockIdx.x;
  for (int i = tid; i < 3200; i += 512){
    int b = i / 100, e4 = i - b*100;
    f32x4 vf = *(const f32x4*)&x1[((size_t)b*256 + t)*400 + e4*4];
    int rb = seq[b] - 1 - t; if (rb < 0) rb = 0;     // clip(L-1-t, 0, T-1)
    f32x4 vb = *(const f32x4*)&x1[((size_t)b*256 + rb)*400 + e4*4];
    short4v sf, sb;
    #pragma unroll
    for (int r = 0; r < 4; r++){ sf[r] = f2bf(vf[r]); sb[r] = f2bf(vb[r]); }
    ((short4v*)xf)[i] = sf;
    ((short4v*)xb)[i] = sb;
  }
  __syncthreads();
  const int lane = tid & 63, wv = tid >> 6;
  const int dir = wv >> 2, wl = wv & 3;
  const u16* xs = dir ? xb : xf;
  const u16* W  = dir ? wihbb : wihfb;
  const float* bg = dir ? bgb : bgf;
  u16* xW = dir ? xWb : xWf;
  const int q = lane & 15, kg = lane >> 4;
  short8v A[2][13];
  #pragma unroll
  for (int mt = 0; mt < 2; mt++)
    #pragma unroll
    for (int ksi = 0; ksi < 13; ksi++){
      int e0 = ksi*32 + kg*8;
      A[mt][ksi] = (e0 < 400) ? *(const short8v*)&xs[(mt*16 + q)*400 + e0] : szero();
    }
  for (int nt = wl; nt < 50; nt += 4){
    int g = nt*16 + q;                       // gate row 0..799 (i,f,g,o blocks of 200)
    float bv = bg[g];
    f32x4 acc0, acc1;
    acc0[0]=bv; acc0[1]=bv; acc0[2]=bv; acc0[3]=bv; acc1 = acc0;
    const u16* wrow = W + (size_t)g*400;
    #pragma unroll
    for (int ksi = 0; ksi < 13; ksi++){
      int e0 = ksi*32 + kg*8;
      short8v bf = (e0 < 400) ? *(const short8v*)&wrow[e0] : szero();
      acc0 = MFMA16(A[0][ksi], bf, acc0, 0,0,0);
      acc1 = MFMA16(A[1][ksi], bf, acc1, 0,0,0);
    }
    int gt = g / 200, hu = g - gt*200;
    #pragma unroll
    for (int r = 0; r < 4; r++){
      int bl = kg*4 + r;                     // D rows = batch rows
      xW[(((size_t)t*32 +      bl)*200 + hu)*4 + gt] = f2bf(acc0[r]);
      xW[(((size_t)t*32 + 16 + bl)*200 + hu)*4 + gt] = f2bf(acc1[r]);
    }
  }
}

// ---------------- K4: sequential BiLSTM, i8 MFMA. grid 16 = (dir2, grp8 of 4 batch). ----------------
__device__ __forceinline__ void store_gate_f32(int p, const i32x4& acc, int q, int kg,
                                               float* gates, const float* scl_s){
  int gt = p/13, nt = p - gt*13;
  int hu0 = nt*16 + kg*4;
  if (hu0 < 200 && q < 4){
    const f32x4 s4 = *(const f32x4*)&scl_s[gt*200 + hu0];
    #pragma unroll
    for (int r = 0; r < 4; r++)
      gates[q*804 + (hu0+r)*4 + gt] = (float)acc[r]*s4[r];
  }
}

__launch_bounds__(512)
__global__ void k4_lstm(const u16* __restrict__ xWf, const u16* __restrict__ xWb,
                        const signed char* __restrict__ w8f, const signed char* __restrict__ w8b,
                        const float* __restrict__ sclf, const float* __restrict__ sclb,
                        const int* __restrict__ seq, float* __restrict__ h_ws){
  __shared__ __align__(16) signed char h8[16*288];   // h_{t-1} i8; rows 4..15 stay zero
  __shared__ __align__(16) float gates[4*804];       // [b4][hu*4+gt], b-stride 804 words
  __shared__ __align__(16) i32x4 pool[20*4*64];      // pairs 32..51 fragment pool (80KB)
  __shared__ float scl_s[800];
  __shared__ int Ls[4];
  const int tid = threadIdx.x;
  const int dir = blockIdx.x >> 3, grp = blockIdx.x & 7;
  const u16* xWd = dir ? xWb : xWf;
  const signed char* w8 = dir ? w8b : w8f;
  const float* scl = dir ? sclb : sclf;
  if (tid < 4) Ls[tid] = seq[grp*4 + tid];
  for (int i = tid; i < 1152; i += 512) ((int*)h8)[i] = 0;
  for (int i = tid; i < 800; i += 512) scl_s[i] = scl[i];
  const int lane = tid & 63, wv = tid >> 6;
  const int q = lane & 15, kg = lane >> 4;
  // pool fill: slot s holds pair p = 32+s (fragment order -> conflict-free b128 reads)
  for (int idx = tid; idx < 20*4*64; idx += 512){
    int s = idx >> 8, rem = idx & 255;
    int ksi = rem >> 6, l = rem & 63;
    int qq = l & 15, kk = l >> 4;
    int p = 32 + s, gt = p/13, nt = p - gt*13;
    pool[idx] = *(const i32x4*)&w8[(size_t)(gt*208 + nt*16 + qq)*256 + ksi*64 + kk*16];
  }
  // register pairs p = wv + 8j, j<4 (64 VGPR)
  i32x4 Wr[4][4];
  #pragma unroll
  for (int j = 0; j < 4; j++){
    int p = wv + 8*j, gt = p/13, nt = p - gt*13;
    #pragma unroll
    for (int ksi = 0; ksi < 4; ksi++)
      Wr[j][ksi] = *(const i32x4*)&w8[(size_t)(gt*208 + nt*16 + q)*256 + ksi*64 + kg*16];
  }
  float cst0 = 0.f, cst1 = 0.f;
  // cell mapping: cell = b*200 + hu over 4 local batches
  const int c0 = tid,        b0c = c0/200, hu0c = c0 - b0c*200;      // always valid
  const int c1 = tid + 512,  b1c = c1/200, hu1c = c1 - b1c*200;      // valid if tid<288
  const int xoff0 = ((grp*4 + b0c)*200 + hu0c)*4;
  const int xoff1 = ((grp*4 + b1c)*200 + hu1c)*4;
  __syncthreads();
  #pragma unroll 1
  for (int t = 0; t < 256; t++){
    // prefetch this step's xW (hides under the MFMA phase)
    const u16* xwt = xWd + (size_t)t*25600;
    short4v xwv0 = *(const short4v*)&xwt[xoff0];
    short4v xwv1; if (tid < 288) xwv1 = *(const short4v*)&xwt[xoff1];
    // h_{t-1} B-fragments
    i32x4 bh[4];
    #pragma unroll
    for (int ksi = 0; ksi < 4; ksi++)
      bh[ksi] = *(const i32x4*)&h8[q*288 + ksi*64 + kg*16];
    // 4 register pairs
    #pragma unroll
    for (int j = 0; j < 4; j++){
      i32x4 acc = {0,0,0,0};
      #pragma unroll
      for (int ksi = 0; ksi < 4; ksi++)
        acc = MFMAI8(Wr[j][ksi], bh[ksi], acc, 0,0,0);
      store_gate_f32(wv + 8*j, acc, q, kg, gates, scl_s);
    }
    // 2 pool pairs (all waves)
    #pragma unroll
    for (int jp = 0; jp < 2; jp++){
      int s = wv + 8*jp;
      i32x4 acc = {0,0,0,0};
      #pragma unroll
      for (int ksi = 0; ksi < 4; ksi++)
        acc = MFMAI8(pool[(s*4 + ksi)*64 + lane], bh[ksi], acc, 0,0,0);
      store_gate_f32(32 + s, acc, q, kg, gates, scl_s);
    }
    // 4 leftover pool pairs on waves 0..3
    if (wv < 4){
      int s = 16 + wv;
      i32x4 acc = {0,0,0,0};
      #pragma unroll
      for (int ksi = 0; ksi < 4; ksi++)
        acc = MFMAI8(pool[(s*4 + ksi)*64 + lane], bh[ksi], acc, 0,0,0);
      store_gate_f32(32 + s, acc, q, kg, gates, scl_s);
    }
    __syncthreads();                               // gates ready
    // activation: 1 cell per thread (2nd cell for tid<288); 1 b128 = all 4 gates
    {
      const f32x4 g4 = *(const f32x4*)&gates[b0c*804 + hu0c*4];
      float gi = g4[0] + bf2f((u16)xwv0[0]);
      float gf = g4[1] + bf2f((u16)xwv0[1]);
      float gg = g4[2] + bf2f((u16)xwv0[2]);
      float go = g4[3] + bf2f((u16)xwv0[3]);
      float c = sigm(gf)*cst0 + sigm(gi)*tanh_u(gg);
      cst0 = c;
      float hv = sigm(go)*tanh_u(c);
      h8[b0c*288 + hu0c] = (signed char)__float2int_rn(hv*127.f);
      int gb = grp*4 + b0c;
      if (dir == 0){
        h_ws[((size_t)gb*256 + t)*400 + hu0c] = hv;
      } else {
        int tp = Ls[b0c] - 1 - t;
        if (tp >= 0) h_ws[((size_t)gb*256 + tp)*400 + 200 + hu0c] = hv;
      }
    }
    if (tid < 288){
      const f32x4 g4 = *(const f32x4*)&gates[b1c*804 + hu1c*4];
      float gi = g4[0] + bf2f((u16)xwv1[0]);
      float gf = g4[1] + bf2f((u16)xwv1[1]);
      float gg = g4[2] + bf2f((u16)xwv1[2]);
      float go = g4[3] + bf2f((u16)xwv1[3]);
      float c = sigm(gf)*cst1 + sigm(gi)*tanh_u(gg);
      cst1 = c;
      float hv = sigm(go)*tanh_u(c);
      h8[b1c*288 + hu1c] = (signed char)__float2int_rn(hv*127.f);
      int gb = grp*4 + b1c;
      if (dir == 0){
        h_ws[((size_t)gb*256 + t)*400 + hu1c] = hv;
      } else {
        int tp = Ls[b1c] - 1 - t;
        if (tp >= 0) h_ws[((size_t)gb*256 + tp)*400 + 200 + hu1c] = hv;
      }
    }
    __syncthreads();                               // h8 ready for t+1
  }
}

// ---------------- K4b: fill bwd rows t>=L with h_bwd_r[0] (== stored row L-1) ----------------
__global__ void k4b_fill(const int* __restrict__ seq, float* __restrict__ h_ws){
  const int b = blockIdx.x;
  const int L = seq[b];
  const int cnt = (256 - L)*200;
  const float* src = h_ws + ((size_t)b*256 + (L-1))*400 + 200;
  for (int i = threadIdx.x; i < cnt; i += 256){
    int tt = L + i/200, cc = i - (i/200)*200;
    h_ws[((size_t)b*256 + tt)*400 + 200 + cc] = src[cc];
  }
}

// ---------------- K5: causal growing-window attention, LDS-tiled (coalesced h reads) ----------------
__launch_bounds__(512)
__global__ void k5_attn(const float* __restrict__ h_ws, const float* __restrict__ wattn,
                        float* __restrict__ x1_att){
  __shared__ float a_lds[256];
  __shared__ float htile[32*401];
  __shared__ float otile[32*401];
  const int tid = threadIdx.x;
  const int b = blockIdx.x;
  const int lane = tid & 63, wv = tid >> 6;
  for (int row = wv*32; row < wv*32 + 32; row++){
    float s = 0.f;
    for (int j = lane; j < 400; j += 64)
      s += h_ws[((size_t)b*256 + row)*400 + j] * wattn[j];
    #pragma unroll
    for (int m = 32; m > 0; m >>= 1) s += __shfl_xor(s, m, 64);
    if (lane == 0) a_lds[row] = s;
  }
  __syncthreads();
  const int col = tid;
  const bool act = col < 400;
  float m = -1e30f, den = 0.f, num = 0.f;
  for (int cc = 0; cc < 8; cc++){
    for (int i = tid; i < 12800; i += 512){
      int r = i / 400, e = i - r*400;
      htile[r*401 + e] = h_ws[((size_t)b*256 + cc*32 + r)*400 + e];
    }
    __syncthreads();
    if (act){
      #pragma unroll 4
      for (int tt = 0; tt < 32; tt++){
        float hv = htile[tt*401 + col];
        float at = a_lds[cc*32 + tt];
        float mn = fmaxf(m, at);
        float rr  = __expf(m - mn);
        float wgt = __expf(at - mn);
        den = den*rr + wgt;
        num = num*rr + wgt*hv;
        m = mn;
        otile[tt*401 + col] = num/den;
      }
    }
    __syncthreads();
    for (int i = tid; i < 12800; i += 512){
      int r = i / 400, e = i - r*400;
      x1_att[((size_t)b*256 + cc*32 + r)*400 + e] = otile[r*401 + e];
    }
    __syncthreads();
  }
}

// ---------------- K6: out = [x1_att ; x2p] @ w_mlp^T + b, masked, f32 ----------------
__global__ void k6_out(const float* __restrict__ x1_att, const float* __restrict__ x2p,
                       const float* __restrict__ wmlp, const float* __restrict__ bmlp,
                       const int* __restrict__ seq, float* __restrict__ out){
  __shared__ float rows[8*800];
  const int tid = threadIdx.x;
  const size_t n0 = (size_t)blockIdx.x*8;
  const int b = (int)(n0 >> 8), t0 = (int)(n0 & 255);
  const int L = seq[b];
  for (int i = tid; i < 3200; i += 256){
    int r = i / 400, e = i - r*400;
    rows[r*800 + e]       = x1_att[(n0 + r)*400 + e];
    rows[r*800 + 400 + e] = x2p  [(n0 + r)*400 + e];
  }
  __syncthreads();
  for (int e = tid; e < 400; e += 256){
    float bv = bmlp[e];
    float acc[8];
    #pragma unroll
    for (int r = 0; r < 8; r++) acc[r] = bv;
    const float* wr = wmlp + (size_t)e*800;
    for (int j = 0; j < 800; j += 4){
      const f32x4 w4 = *(const f32x4*)&wr[j];
      #pragma unroll
      for (int r = 0; r < 8; r++){
        const f32x4 x4 = *(const f32x4*)&rows[r*800 + j];
        acc[r] += x4[0]*w4[0] + x4[1]*w4[1] + x4[2]*w4[2] + x4[3]*w4[3];
      }
    }
    #pragma unroll
    for (int r = 0; r < 8; r++){
      float v = (t0 + r < L) ? acc[r] : 0.f;
      out[(n0 + r)*400 + e] = v;
    }
  }
}

extern "C" void kernel_launch(void* const* d_in, const int* in_sizes, int n_in,
                              void* d_out, int out_size, void* d_ws, size_t ws_size,
                              hipStream_t stream){
  const float* x1   = (const float*)d_in[0];
  const float* x2   = (const float*)d_in[1];
  // d_in[2] = cate: unused by the reference
  const int*   seq  = (const int*)d_in[3];
  const float* wihf = (const float*)d_in[4];
  const float* whhf = (const float*)d_in[5];
  const float* bihf = (const float*)d_in[6];
  const float* bhhf = (const float*)d_in[7];
  const float* wihb = (const float*)d_in[8];
  const float* whhb = (const float*)d_in[9];
  const float* bihb = (const float*)d_in[10];
  const float* bhhb = (const float*)d_in[11];
  const float* wq   = (const float*)d_in[12];
  const float* bq   = (const float*)d_in[13];
  const float* wk   = (const float*)d_in[14];
  const float* bk   = (const float*)d_in[15];
  const float* wmha = (const float*)d_in[16];
  const float* bmha = (const float*)d_in[17];
  const float* wattn= (const float*)d_in[18];
  // d_in[19] = b_attn: cancels in softmax
  const float* wmlp = (const float*)d_in[20];
  const float* bmlp = (const float*)d_in[21];
  float* out = (float*)d_out;

  char* ws = (char*)d_ws;
  u16*  wqb    = (u16*)(ws + 0);              // 320,000 B
  u16*  wkb    = (u16*)(ws + 320000);         // 320,000
  u16*  wihfb  = (u16*)(ws + 640000);         // 640,000
  u16*  wihbb  = (u16*)(ws + 1280000);        // 640,000
  signed char* w8f  = (signed char*)(ws + 1920000);  // 212,992 (4*208*256)
  signed char* w8b  = (signed char*)(ws + 2132992);  // 212,992
  float* sclf  = (float*)(ws + 2345984);      // 3,200
  float* sclb  = (float*)(ws + 2349184);      // 3,200
  float* bgf   = (float*)(ws + 2352384);      // 3,200
  float* bgb   = (float*)(ws + 2355584);      // 3,200 -> end 2,358,784
  float* pooled= (float*)(ws + 2359296);      // 13,107,200
  float* x2p   = (float*)(ws + 15466496);     // 13,107,200
  u16*  xWf    = (u16*)(ws + 28573696);       // 13,107,200
  u16*  xWb    = (u16*)(ws + 41680896);       // 13,107,200
  float* h_ws  = (float*)(ws + 54788096);     // 13,107,200 (end ~67.9MB)
  float* x1_att= (float*)(ws + 28573696);     // overlay: xWf dead after k4

  k0_cvt  <<<dim3(1250), dim3(256), 0, stream>>>(wq, wk, wihf, wihb,
                                                 bihf, bhhf, bihb, bhhb,
                                                 wqb, wkb, wihfb, wihbb, bgf, bgb);
  k0b_quant<<<dim3(416), dim3(256), 0, stream>>>(whhf, whhb, w8f, w8b, sclf, sclb);
  k1_pool <<<dim3(4096), dim3(256), 0, stream>>>(x2, wqb, bq, wkb, bk, pooled);
  k3_xw   <<<dim3(256),  dim3(512), 0, stream>>>(x1, seq, wihfb, wihbb, bgf, bgb, xWf, xWb);
  k2_x2p  <<<dim3(1024), dim3(256), 0, stream>>>(pooled, wmha, bmha, x2p);
  k4_lstm <<<dim3(16),   dim3(512), 0, stream>>>(xWf, xWb, w8f, w8b, sclf, sclb, seq, h_ws);
  k4b_fill<<<dim3(32),   dim3(256), 0, stream>>>(seq, h_ws);
  k5_attn <<<dim3(32),   dim3(512), 0, stream>>>(h_ws, wattn, x1_att);
  k6_out  <<<dim3(1024), dim3(256), 0, stream>>>(x1_att, x2p, wmlp, bmlp, seq, out);
}